// Round 16
// baseline (303.534 us; speedup 1.0000x reference)
//
#include <hip/hip_runtime.h>
#include <hip/hip_bf16.h>

#define S_LEN 2048
#define DM 1024
#define NH 16
#define DH 64
#define MTOK 4096

typedef __attribute__((ext_vector_type(8))) __bf16 bf16x8;
typedef __attribute__((ext_vector_type(4))) float f32x4;
typedef unsigned short u16;
typedef unsigned long long u64;

__device__ __forceinline__ u16 f2bf(float f) {
  union { float f; unsigned u; } a; a.f = f;
  unsigned u = a.u;
  u += 0x7fffu + ((u >> 16) & 1u);   // RNE
  return (u16)(u >> 16);
}

__device__ __forceinline__ bf16x8 ld_bf8(const u16* p) {
  return *reinterpret_cast<const bf16x8*>(p);
}

// compile-time component access (no address-taking -> stays in registers, rule #20)
__device__ __forceinline__ float f4get(const float4& v, int r) {
  switch (r & 3) { case 0: return v.x; case 1: return v.y; case 2: return v.z; default: return v.w; }
}

// ---------------- fused fp32 -> bf16 convert: 7 arrays in one launch ----------------
__global__ void k_convert_all(
    const float* __restrict__ w_q, const float* __restrict__ w_k,
    const float* __restrict__ w_v, const float* __restrict__ w_o,
    const float* __restrict__ q, const float* __restrict__ k, const float* __restrict__ v,
    u16* __restrict__ dwq, u16* __restrict__ dwk, u16* __restrict__ dwv,
    u16* __restrict__ dwo, u16* __restrict__ dq, u16* __restrict__ dk, u16* __restrict__ dv,
    int n4w, int n4x) {
  const int z = blockIdx.y;
  const float* s; u16* d; int n4;
  switch (z) {
    case 0: s = w_q; d = dwq; n4 = n4w; break;
    case 1: s = w_k; d = dwk; n4 = n4w; break;
    case 2: s = w_v; d = dwv; n4 = n4w; break;
    case 3: s = w_o; d = dwo; n4 = n4w; break;
    case 4: s = q;   d = dq;  n4 = n4x; break;
    case 5: s = k;   d = dk;  n4 = n4x; break;
    default: s = v;  d = dv;  n4 = n4x; break;
  }
  int i = blockIdx.x * blockDim.x + threadIdx.x;
  const int stride = gridDim.x * blockDim.x;
  for (; i < n4; i += stride) {
    float4 vv = reinterpret_cast<const float4*>(s)[i];
    ushort4 o;
    o.x = f2bf(vv.x); o.y = f2bf(vv.y); o.z = f2bf(vv.z); o.w = f2bf(vv.w);
    reinterpret_cast<ushort4*>(d)[i] = o;
  }
}

// ---------------- mask bit-pack: [B][S][S] i32 -> [B][S][S/64] u64 ----------------
__global__ void k_maskpack(const int* __restrict__ m, u64* __restrict__ o, int n) {
  int i = blockIdx.x * blockDim.x + threadIdx.x;
  int stride = gridDim.x * blockDim.x;
  for (; i < n; i += stride) {
    u64 bal = __ballot(m[i] != 0);
    if ((i & 63) == 0) o[i >> 6] = bal;
  }
}

// ---------------- fused QKV GEMM: z = 0 (Q), 1 (K), 2 (V, transposed out) ----------
__global__ __launch_bounds__(256) void k_gemm_qkv(
    const u16* __restrict__ xq, const u16* __restrict__ xk, const u16* __restrict__ xv,
    const u16* __restrict__ wq, const u16* __restrict__ wk, const u16* __restrict__ wv,
    const float* __restrict__ bq, const float* __restrict__ bk, const float* __restrict__ bvb,
    u16* __restrict__ Qd, u16* __restrict__ Kd, u16* __restrict__ Vd) {
  constexpr int K = DM;
  __shared__ u16 As[128 * 32];
  __shared__ u16 Bs[128 * 32];
  const int z = blockIdx.z;
  const u16* A  = z == 0 ? xq : z == 1 ? xk : xv;
  const u16* Bw = z == 0 ? wq : z == 1 ? wk : wv;
  const float* bias = z == 0 ? bq : z == 1 ? bk : bvb;
  const int tid = threadIdx.x;
  const int lane = tid & 63;
  const int wid = tid >> 6;
  const int wm = wid >> 1, wn = wid & 1;
  const int bm = blockIdx.x * 128;
  const int bn = blockIdx.y * 128;
  const int r0 = tid >> 2;
  const int c0 = (tid & 3) * 8;
  const int fr = lane & 15;
  const int fk = (lane >> 4) * 8;

  f32x4 acc[4][4] = {};

  const u16* ga = A + (size_t)(bm + r0) * K + c0;
  const u16* gb = Bw + (size_t)(bn + r0) * K + c0;

  for (int kt = 0; kt < K; kt += 32) {
    __syncthreads();
    __builtin_amdgcn_global_load_lds(
        (const __attribute__((address_space(1))) void*)(ga + kt),
        (__attribute__((address_space(3))) void*)(&As[r0 * 32 + c0]), 16, 0, 0);
    __builtin_amdgcn_global_load_lds(
        (const __attribute__((address_space(1))) void*)(ga + (size_t)64 * K + kt),
        (__attribute__((address_space(3))) void*)(&As[(r0 + 64) * 32 + c0]), 16, 0, 0);
    __builtin_amdgcn_global_load_lds(
        (const __attribute__((address_space(1))) void*)(gb + kt),
        (__attribute__((address_space(3))) void*)(&Bs[r0 * 32 + c0]), 16, 0, 0);
    __builtin_amdgcn_global_load_lds(
        (const __attribute__((address_space(1))) void*)(gb + (size_t)64 * K + kt),
        (__attribute__((address_space(3))) void*)(&Bs[(r0 + 64) * 32 + c0]), 16, 0, 0);
    __syncthreads();
    bf16x8 af[4], bfr[4];
#pragma unroll
    for (int m = 0; m < 4; ++m) af[m] = ld_bf8(&As[(wm * 64 + m * 16 + fr) * 32 + fk]);
#pragma unroll
    for (int n = 0; n < 4; ++n) bfr[n] = ld_bf8(&Bs[(wn * 64 + n * 16 + fr) * 32 + fk]);
#pragma unroll
    for (int m = 0; m < 4; ++m)
#pragma unroll
      for (int n = 0; n < 4; ++n)
        acc[m][n] = __builtin_amdgcn_mfma_f32_16x16x32_bf16(af[m], bfr[n], acc[m][n], 0, 0, 0);
  }

  const int cr = (lane >> 4) * 4;
  const int cc = lane & 15;
#pragma unroll
  for (int m = 0; m < 4; ++m) {
#pragma unroll
    for (int n = 0; n < 4; ++n) {
      const int colg = bn + wn * 64 + n * 16 + cc;
      const float bv = bias[colg];
      const int rbase = bm + wm * 64 + m * 16 + cr;
      const int hh = colg >> 6, d = colg & 63;
      if (z < 2) {
        u16* o = z == 0 ? Qd : Kd;
#pragma unroll
        for (int r = 0; r < 4; ++r) {
          const int tok = rbase + r;
          const int b = tok >> 11, s = tok & 2047;
          o[(((size_t)(b * NH + hh) * S_LEN) + s) * DH + d] = f2bf(acc[m][n][r] + bv);
        }
      } else {
        const int tok = rbase;
        const int b = tok >> 11, s = tok & 2047;
        ushort4 pk;
        pk.x = f2bf(acc[m][n][0] + bv);
        pk.y = f2bf(acc[m][n][1] + bv);
        pk.z = f2bf(acc[m][n][2] + bv);
        pk.w = f2bf(acc[m][n][3] + bv);
        *reinterpret_cast<ushort4*>(&Vd[(((size_t)(b * NH + hh) * DH) + d) * S_LEN + s]) = pk;
      }
    }
  }
}

// ---------------- output GEMM: C = ctx @ Wo^T + bias (fp32 out) ----------------
__global__ __launch_bounds__(256) void k_gemm_out(
    const u16* __restrict__ A, const u16* __restrict__ Bw,
    const float* __restrict__ bias, float* __restrict__ dst) {
  constexpr int K = DM;
  __shared__ u16 As[128 * 32];
  __shared__ u16 Bs[128 * 32];
  const int tid = threadIdx.x;
  const int lane = tid & 63;
  const int wid = tid >> 6;
  const int wm = wid >> 1, wn = wid & 1;
  const int bm = blockIdx.x * 128;
  const int bn = blockIdx.y * 128;
  const int r0 = tid >> 2;
  const int c0 = (tid & 3) * 8;
  const int fr = lane & 15;
  const int fk = (lane >> 4) * 8;

  f32x4 acc[4][4] = {};

  const u16* ga = A + (size_t)(bm + r0) * K + c0;
  const u16* gb = Bw + (size_t)(bn + r0) * K + c0;

  for (int kt = 0; kt < K; kt += 32) {
    __syncthreads();
    __builtin_amdgcn_global_load_lds(
        (const __attribute__((address_space(1))) void*)(ga + kt),
        (__attribute__((address_space(3))) void*)(&As[r0 * 32 + c0]), 16, 0, 0);
    __builtin_amdgcn_global_load_lds(
        (const __attribute__((address_space(1))) void*)(ga + (size_t)64 * K + kt),
        (__attribute__((address_space(3))) void*)(&As[(r0 + 64) * 32 + c0]), 16, 0, 0);
    __builtin_amdgcn_global_load_lds(
        (const __attribute__((address_space(1))) void*)(gb + kt),
        (__attribute__((address_space(3))) void*)(&Bs[r0 * 32 + c0]), 16, 0, 0);
    __builtin_amdgcn_global_load_lds(
        (const __attribute__((address_space(1))) void*)(gb + (size_t)64 * K + kt),
        (__attribute__((address_space(3))) void*)(&Bs[(r0 + 64) * 32 + c0]), 16, 0, 0);
    __syncthreads();
    bf16x8 af[4], bfr[4];
#pragma unroll
    for (int m = 0; m < 4; ++m) af[m] = ld_bf8(&As[(wm * 64 + m * 16 + fr) * 32 + fk]);
#pragma unroll
    for (int n = 0; n < 4; ++n) bfr[n] = ld_bf8(&Bs[(wn * 64 + n * 16 + fr) * 32 + fk]);
#pragma unroll
    for (int m = 0; m < 4; ++m)
#pragma unroll
      for (int n = 0; n < 4; ++n)
        acc[m][n] = __builtin_amdgcn_mfma_f32_16x16x32_bf16(af[m], bfr[n], acc[m][n], 0, 0, 0);
  }

  const int cr = (lane >> 4) * 4;
  const int cc = lane & 15;
#pragma unroll
  for (int m = 0; m < 4; ++m) {
#pragma unroll
    for (int n = 0; n < 4; ++n) {
      const int colg = bn + wn * 64 + n * 16 + cc;
      const float bv = bias[colg];
      const int rbase = bm + wm * 64 + m * 16 + cr;
#pragma unroll
      for (int r = 0; r < 4; ++r)
        dst[(size_t)(rbase + r) * DM + colg] = acc[m][n][r] + bv;
    }
  }
}

// ---------------- fused flash attention: T15 cross-tile PV pipeline ----------------
// Iter t: QK(t) + exp(t) -> pa(t); PV(t-1) executes with pa(t-1) — independent
// of iter-t's serial chain, so MFMA(PV) overlaps VALU(softmax) and fills stalls.
// V triple-buffered (K dbuf + V tribuf = 40 KB LDS, still 4 blocks/CU).
// Counted-vmcnt barrier: vmcnt(5) drains the 4 stage loads, keeps 5 bias/mask
// prefetches in flight across the barrier (R8-proven pattern).
__global__ __launch_bounds__(256, 4) void k_attn(
    const u16* __restrict__ Qb, const u16* __restrict__ Kb, const u16* __restrict__ Vt,
    const float* __restrict__ bias, const u64* __restrict__ mpk,
    u16* __restrict__ ctx) {
  __shared__ u16 lds[5 * 4096];   // [0,1]=K dbuf; [2,3,4]=V tribuf
  const int tid = threadIdx.x;
  const int lane = tid & 63;
  const int w = tid >> 6;
  const int b = blockIdx.z;
  const int h = blockIdx.y;
  const int q0 = blockIdx.x * 64 + w * 16;
  const int lq = lane & 15;
  const int lg = lane >> 4;

  const float* bp = bias + (size_t)h * S_LEN * S_LEN;
  const u16* Kp = Kb + (size_t)(b * NH + h) * S_LEN * DH;
  const u16* Vp = Vt + (size_t)(b * NH + h) * DH * S_LEN;

  bf16x8 qf[2];
  f32x4 cacc[4] = {};
  float l_run = 0.f;
  {
    const u16* Qp = Qb + (size_t)(b * NH + h) * S_LEN * DH;
    qf[0] = ld_bf8(&Qp[(size_t)(q0 + lq) * DH + lg * 8]);
    qf[1] = ld_bf8(&Qp[(size_t)(q0 + lq) * DH + 32 + lg * 8]);
  }

#define STAGE(ktv, KOFF, VOFF) {                                                  \
    _Pragma("unroll") for (int i = 0; i < 2; ++i) {                               \
      const int el = (i * 256 + tid) * 8;                                         \
      const int rr = el >> 6;                                                     \
      const int ce = ((tid & 7) * 8) ^ ((rr & 7) << 3);                           \
      const u16* ksrc = Kp + (size_t)((ktv) + rr) * DH + ce;                      \
      const u16* vsrc = Vp + (size_t)rr * S_LEN + (ktv) + ce;                     \
      __builtin_amdgcn_global_load_lds(                                           \
          (const __attribute__((address_space(1))) void*)ksrc,                    \
          (__attribute__((address_space(3))) void*)&lds[(KOFF) + el], 16, 0, 0);  \
      __builtin_amdgcn_global_load_lds(                                           \
          (const __attribute__((address_space(1))) void*)vsrc,                    \
          (__attribute__((address_space(3))) void*)&lds[(VOFF) + el], 16, 0, 0);  \
    } }

#define SWZ(row, col) ((row) * 64 + (((((col) >> 3) ^ ((row) & 7)) << 3) | ((col) & 7)))

#define LOADB(ktv, tv) {                                                          \
    bv0 = *reinterpret_cast<const float4*>(                                       \
        &bp[(size_t)(q0 + lq) * S_LEN + (ktv) + 0 * 16 + lg * 4]);                \
    bv1 = *reinterpret_cast<const float4*>(                                       \
        &bp[(size_t)(q0 + lq) * S_LEN + (ktv) + 1 * 16 + lg * 4]);                \
    bv2 = *reinterpret_cast<const float4*>(                                       \
        &bp[(size_t)(q0 + lq) * S_LEN + (ktv) + 2 * 16 + lg * 4]);                \
    bv3 = *reinterpret_cast<const float4*>(                                       \
        &bp[(size_t)(q0 + lq) * S_LEN + (ktv) + 3 * 16 + lg * 4]);                \
    mw = mpk[((size_t)(b * S_LEN + q0 + lq)) * 32 + (tv)]; }

// PV for tile (t-1): A = pa regs, B = V^T rows from LDS offset VOFF
#define PVSTEP(VOFF, PA0, PA1) {                                                  \
    __builtin_amdgcn_s_setprio(1);                                                \
    _Pragma("unroll") for (int nd = 0; nd < 4; ++nd) {                            \
      _Pragma("unroll") for (int p = 0; p < 2; ++p) {                             \
        union { unsigned u[4]; bf16x8 v; } vu;                                    \
        const unsigned* vp0 = reinterpret_cast<const unsigned*>(                  \
            &lds[(VOFF) + SWZ(nd * 16 + lq, (2 * p) * 16 + lg * 4)]);             \
        const unsigned* vp1 = reinterpret_cast<const unsigned*>(                  \
            &lds[(VOFF) + SWZ(nd * 16 + lq, (2 * p + 1) * 16 + lg * 4)]);         \
        vu.u[0] = vp0[0]; vu.u[1] = vp0[1];                                       \
        vu.u[2] = vp1[0]; vu.u[3] = vp1[1];                                       \
        cacc[nd] = __builtin_amdgcn_mfma_f32_16x16x32_bf16(p ? PA1 : PA0, vu.v,   \
                                                           cacc[nd], 0, 0, 0);    \
      }                                                                           \
    }                                                                             \
    __builtin_amdgcn_s_setprio(0); }

  float4 bv0, bv1, bv2, bv3;
  u64 mw;
  bf16x8 paA0, paA1, paB0, paB1;
  int kc = 0;                    // K read buf (0 / 4096)
  int vprv = 4 * 4096;           // V(t-1)  [garbage at t=0, unused]
  int vcur = 2 * 4096;           // V(t)
  int vstg = 3 * 4096;           // V(t+1) stage dest

  STAGE(0, kc, vcur);
  LOADB(0, 0);

  for (int t = 0; t < S_LEN / 64; ++t) {
    // counted-vmcnt barrier: drain 4 stage loads, keep 5 bias/mask in flight
    asm volatile("s_waitcnt vmcnt(5) lgkmcnt(0)" ::: "memory");
    __builtin_amdgcn_sched_barrier(0);
    __builtin_amdgcn_s_barrier();
    __builtin_amdgcn_sched_barrier(0);

    if (t + 1 < S_LEN / 64) {
      STAGE(t * 64 + 64, kc ^ 4096, vstg);
      __builtin_amdgcn_sched_barrier(0);
    }

    // ---- S^T = K Q^T from K buf kc ----
    f32x4 sc[4];
    __builtin_amdgcn_s_setprio(1);
#pragma unroll
    for (int nb = 0; nb < 4; ++nb) {
      bf16x8 kf0 = ld_bf8(&lds[kc + SWZ(nb * 16 + lq, lg * 8)]);
      bf16x8 kf1 = ld_bf8(&lds[kc + SWZ(nb * 16 + lq, 32 + lg * 8)]);
      f32x4 z = {};
      z = __builtin_amdgcn_mfma_f32_16x16x32_bf16(kf0, qf[0], z, 0, 0, 0);
      sc[nb] = __builtin_amdgcn_mfma_f32_16x16x32_bf16(kf1, qf[1], z, 0, 0, 0);
    }
    __builtin_amdgcn_s_setprio(0);

    // ---- scale + bias + mask; consumes bv/mw of tile t ----
#pragma unroll
    for (int r = 0; r < 4; ++r) {
      const int sh = lg * 4 + r;
      sc[0][r] = ((mw >> (sh))      & 1) ? sc[0][r] * 0.125f + f4get(bv0, r) : -1e9f;
      sc[1][r] = ((mw >> (16 + sh)) & 1) ? sc[1][r] * 0.125f + f4get(bv1, r) : -1e9f;
      sc[2][r] = ((mw >> (32 + sh)) & 1) ? sc[2][r] * 0.125f + f4get(bv2, r) : -1e9f;
      sc[3][r] = ((mw >> (48 + sh)) & 1) ? sc[3][r] * 0.125f + f4get(bv3, r) : -1e9f;
    }
    // ---- issue next tile's bias/mask ----
    if (t + 1 < S_LEN / 64) LOADB(t * 64 + 64, t + 1);

    // ---- exp (no-max, scores bounded) + sum ----
    float s0 = 0.f;
#pragma unroll
    for (int nb = 0; nb < 4; ++nb)
#pragma unroll
      for (int r = 0; r < 4; ++r) {
        const float p = __expf(sc[nb][r]);
        sc[nb][r] = p;
        s0 += p;
      }
    s0 += __shfl_xor(s0, 16);
    s0 += __shfl_xor(s0, 32);
    l_run += s0;

    // ---- PV(t-1): independent MFMA stream overlapping this iter's softmax ----
    if (t > 0) PVSTEP(vprv, paA0, paA1);

    // ---- pack P(t) in-lane (hardware cvt_pk via __bf16 casts) ----
    {
      union { __bf16 e[8]; bf16x8 v; } pu;
      pu.e[0] = (__bf16)sc[0][0]; pu.e[1] = (__bf16)sc[0][1];
      pu.e[2] = (__bf16)sc[0][2]; pu.e[3] = (__bf16)sc[0][3];
      pu.e[4] = (__bf16)sc[1][0]; pu.e[5] = (__bf16)sc[1][1];
      pu.e[6] = (__bf16)sc[1][2]; pu.e[7] = (__bf16)sc[1][3];
      paB0 = pu.v;
      pu.e[0] = (__bf16)sc[2][0]; pu.e[1] = (__bf16)sc[2][1];
      pu.e[2] = (__bf16)sc[2][2]; pu.e[3] = (__bf16)sc[2][3];
      pu.e[4] = (__bf16)sc[3][0]; pu.e[5] = (__bf16)sc[3][1];
      pu.e[6] = (__bf16)sc[3][2]; pu.e[7] = (__bf16)sc[3][3];
      paB1 = pu.v;
    }
    paA0 = paB0; paA1 = paB1;

    // ---- rotate buffers ----
    kc ^= 4096;
    const int vtmp = vprv; vprv = vcur; vcur = vstg; vstg = vtmp;
  }
  // ---- final PV for tile 31 (vprv = vbuf(31) after last rotation) ----
  PVSTEP(vprv, paA0, paA1);
#undef STAGE
#undef SWZ
#undef LOADB
#undef PVSTEP

  // ---- epilogue: cacc row q = lg*4+r, col d = nd*16+lq ----
#pragma unroll
  for (int r = 0; r < 4; ++r) {
    const float linv = 1.0f / __shfl(l_run, lg * 4 + r);
    const int tok = b * S_LEN + q0 + lg * 4 + r;
    u16* cp = ctx + (size_t)tok * DM + h * DH;
#pragma unroll
    for (int nd = 0; nd < 4; ++nd)
      cp[nd * 16 + lq] = f2bf(cacc[nd][r] * linv);
  }
}

extern "C" void kernel_launch(void* const* d_in, const int* in_sizes, int n_in,
                              void* d_out, int out_size, void* d_ws, size_t ws_size,
                              hipStream_t stream) {
  const float* q   = (const float*)d_in[0];
  const float* k   = (const float*)d_in[1];
  const float* v   = (const float*)d_in[2];
  const int*   msk = (const int*)d_in[3];
  const float* pb  = (const float*)d_in[4];
  const float* w_q = (const float*)d_in[5];
  const float* b_q = (const float*)d_in[6];
  const float* w_k = (const float*)d_in[7];
  const float* b_k = (const float*)d_in[8];
  const float* w_v = (const float*)d_in[9];
  const float* b_v = (const float*)d_in[10];
  const float* w_o = (const float*)d_in[11];
  const float* b_o = (const float*)d_in[12];
  float* out = (float*)d_out;

  char* ws = (char*)d_ws;
  u16* wq_bf = (u16*)(ws + ((size_t)0 << 20));
  u16* wk_bf = (u16*)(ws + ((size_t)2 << 20));
  u16* wv_bf = (u16*)(ws + ((size_t)4 << 20));
  u16* wo_bf = (u16*)(ws + ((size_t)6 << 20));
  u16* xq    = (u16*)(ws + ((size_t)8 << 20));   // reused as ctx after QKV gemm
  u16* xk    = (u16*)(ws + ((size_t)16 << 20));
  u16* xv    = (u16*)(ws + ((size_t)24 << 20));
  u16* Qb    = (u16*)(ws + ((size_t)32 << 20));
  u16* Kb    = (u16*)(ws + ((size_t)40 << 20));
  u16* Vtb   = (u16*)(ws + ((size_t)48 << 20));
  u64* mpk   = (u64*)(ws + ((size_t)56 << 20));  // 1 MB packed mask

  dim3 blk(256);
  const int n4w = DM * DM / 4;
  const int n4x = MTOK * DM / 4;

  k_convert_all<<<dim3(512, 7), blk, 0, stream>>>(
      w_q, w_k, w_v, w_o, q, k, v,
      wq_bf, wk_bf, wv_bf, wo_bf, xq, xk, xv, n4w, n4x);
  k_maskpack<<<dim3(2048), blk, 0, stream>>>(msk, mpk, 2 * S_LEN * S_LEN);

  k_gemm_qkv<<<dim3(32, 8, 3), blk, 0, stream>>>(
      xq, xk, xv, wq_bf, wk_bf, wv_bf, b_q, b_k, b_v, Qb, Kb, Vtb);

  k_attn<<<dim3(32, NH, 2), blk, 0, stream>>>(Qb, Kb, Vtb, pb, mpk, xq);
  k_gemm_out<<<dim3(32, 8), blk, 0, stream>>>(xq, wo_bf, b_o, out);
}

// Round 17
// 234.177 us; speedup vs baseline: 1.2962x; 1.2962x over previous
//
#include <hip/hip_runtime.h>
#include <hip/hip_bf16.h>

#define S_LEN 2048
#define DM 1024
#define NH 16
#define DH 64
#define MTOK 4096

typedef __attribute__((ext_vector_type(8))) __bf16 bf16x8;
typedef __attribute__((ext_vector_type(4))) float f32x4;
typedef unsigned short u16;
typedef unsigned long long u64;

__device__ __forceinline__ u16 f2bf(float f) {
  union { float f; unsigned u; } a; a.f = f;
  unsigned u = a.u;
  u += 0x7fffu + ((u >> 16) & 1u);   // RNE
  return (u16)(u >> 16);
}

__device__ __forceinline__ bf16x8 ld_bf8(const u16* p) {
  return *reinterpret_cast<const bf16x8*>(p);
}

// compile-time component access (no address-taking -> stays in registers, rule #20)
__device__ __forceinline__ float f4get(const float4& v, int r) {
  switch (r & 3) { case 0: return v.x; case 1: return v.y; case 2: return v.z; default: return v.w; }
}

// ---------------- fused fp32 -> bf16 convert: 7 arrays in one launch ----------------
__global__ void k_convert_all(
    const float* __restrict__ w_q, const float* __restrict__ w_k,
    const float* __restrict__ w_v, const float* __restrict__ w_o,
    const float* __restrict__ q, const float* __restrict__ k, const float* __restrict__ v,
    u16* __restrict__ dwq, u16* __restrict__ dwk, u16* __restrict__ dwv,
    u16* __restrict__ dwo, u16* __restrict__ dq, u16* __restrict__ dk, u16* __restrict__ dv,
    int n4w, int n4x) {
  const int z = blockIdx.y;
  const float* s; u16* d; int n4;
  switch (z) {
    case 0: s = w_q; d = dwq; n4 = n4w; break;
    case 1: s = w_k; d = dwk; n4 = n4w; break;
    case 2: s = w_v; d = dwv; n4 = n4w; break;
    case 3: s = w_o; d = dwo; n4 = n4w; break;
    case 4: s = q;   d = dq;  n4 = n4x; break;
    case 5: s = k;   d = dk;  n4 = n4x; break;
    default: s = v;  d = dv;  n4 = n4x; break;
  }
  int i = blockIdx.x * blockDim.x + threadIdx.x;
  const int stride = gridDim.x * blockDim.x;
  for (; i < n4; i += stride) {
    float4 vv = reinterpret_cast<const float4*>(s)[i];
    ushort4 o;
    o.x = f2bf(vv.x); o.y = f2bf(vv.y); o.z = f2bf(vv.z); o.w = f2bf(vv.w);
    reinterpret_cast<ushort4*>(d)[i] = o;
  }
}

// ---------------- mask bit-pack: [B][S][S] i32 -> [B][S][S/64] u64 ----------------
__global__ void k_maskpack(const int* __restrict__ m, u64* __restrict__ o, int n) {
  int i = blockIdx.x * blockDim.x + threadIdx.x;
  int stride = gridDim.x * blockDim.x;
  for (; i < n; i += stride) {
    u64 bal = __ballot(m[i] != 0);
    if ((i & 63) == 0) o[i >> 6] = bal;
  }
}

// ---------------- fused QKV GEMM: z = 0 (Q), 1 (K), 2 (V, transposed out) ----------
__global__ __launch_bounds__(256) void k_gemm_qkv(
    const u16* __restrict__ xq, const u16* __restrict__ xk, const u16* __restrict__ xv,
    const u16* __restrict__ wq, const u16* __restrict__ wk, const u16* __restrict__ wv,
    const float* __restrict__ bq, const float* __restrict__ bk, const float* __restrict__ bvb,
    u16* __restrict__ Qd, u16* __restrict__ Kd, u16* __restrict__ Vd) {
  constexpr int K = DM;
  __shared__ u16 As[128 * 32];
  __shared__ u16 Bs[128 * 32];
  const int z = blockIdx.z;
  const u16* A  = z == 0 ? xq : z == 1 ? xk : xv;
  const u16* Bw = z == 0 ? wq : z == 1 ? wk : wv;
  const float* bias = z == 0 ? bq : z == 1 ? bk : bvb;
  const int tid = threadIdx.x;
  const int lane = tid & 63;
  const int wid = tid >> 6;
  const int wm = wid >> 1, wn = wid & 1;
  const int bm = blockIdx.x * 128;
  const int bn = blockIdx.y * 128;
  const int r0 = tid >> 2;
  const int c0 = (tid & 3) * 8;
  const int fr = lane & 15;
  const int fk = (lane >> 4) * 8;

  f32x4 acc[4][4] = {};

  const u16* ga = A + (size_t)(bm + r0) * K + c0;
  const u16* gb = Bw + (size_t)(bn + r0) * K + c0;

  for (int kt = 0; kt < K; kt += 32) {
    __syncthreads();
    __builtin_amdgcn_global_load_lds(
        (const __attribute__((address_space(1))) void*)(ga + kt),
        (__attribute__((address_space(3))) void*)(&As[r0 * 32 + c0]), 16, 0, 0);
    __builtin_amdgcn_global_load_lds(
        (const __attribute__((address_space(1))) void*)(ga + (size_t)64 * K + kt),
        (__attribute__((address_space(3))) void*)(&As[(r0 + 64) * 32 + c0]), 16, 0, 0);
    __builtin_amdgcn_global_load_lds(
        (const __attribute__((address_space(1))) void*)(gb + kt),
        (__attribute__((address_space(3))) void*)(&Bs[r0 * 32 + c0]), 16, 0, 0);
    __builtin_amdgcn_global_load_lds(
        (const __attribute__((address_space(1))) void*)(gb + (size_t)64 * K + kt),
        (__attribute__((address_space(3))) void*)(&Bs[(r0 + 64) * 32 + c0]), 16, 0, 0);
    __syncthreads();
    bf16x8 af[4], bfr[4];
#pragma unroll
    for (int m = 0; m < 4; ++m) af[m] = ld_bf8(&As[(wm * 64 + m * 16 + fr) * 32 + fk]);
#pragma unroll
    for (int n = 0; n < 4; ++n) bfr[n] = ld_bf8(&Bs[(wn * 64 + n * 16 + fr) * 32 + fk]);
#pragma unroll
    for (int m = 0; m < 4; ++m)
#pragma unroll
      for (int n = 0; n < 4; ++n)
        acc[m][n] = __builtin_amdgcn_mfma_f32_16x16x32_bf16(af[m], bfr[n], acc[m][n], 0, 0, 0);
  }

  const int cr = (lane >> 4) * 4;
  const int cc = lane & 15;
#pragma unroll
  for (int m = 0; m < 4; ++m) {
#pragma unroll
    for (int n = 0; n < 4; ++n) {
      const int colg = bn + wn * 64 + n * 16 + cc;
      const float bv = bias[colg];
      const int rbase = bm + wm * 64 + m * 16 + cr;
      const int hh = colg >> 6, d = colg & 63;
      if (z < 2) {
        u16* o = z == 0 ? Qd : Kd;
#pragma unroll
        for (int r = 0; r < 4; ++r) {
          const int tok = rbase + r;
          const int b = tok >> 11, s = tok & 2047;
          o[(((size_t)(b * NH + hh) * S_LEN) + s) * DH + d] = f2bf(acc[m][n][r] + bv);
        }
      } else {
        const int tok = rbase;
        const int b = tok >> 11, s = tok & 2047;
        ushort4 pk;
        pk.x = f2bf(acc[m][n][0] + bv);
        pk.y = f2bf(acc[m][n][1] + bv);
        pk.z = f2bf(acc[m][n][2] + bv);
        pk.w = f2bf(acc[m][n][3] + bv);
        *reinterpret_cast<ushort4*>(&Vd[(((size_t)(b * NH + hh) * DH) + d) * S_LEN + s]) = pk;
      }
    }
  }
}

// ---------------- output GEMM: C = ctx @ Wo^T + bias (fp32 out) ----------------
__global__ __launch_bounds__(256) void k_gemm_out(
    const u16* __restrict__ A, const u16* __restrict__ Bw,
    const float* __restrict__ bias, float* __restrict__ dst) {
  constexpr int K = DM;
  __shared__ u16 As[128 * 32];
  __shared__ u16 Bs[128 * 32];
  const int tid = threadIdx.x;
  const int lane = tid & 63;
  const int wid = tid >> 6;
  const int wm = wid >> 1, wn = wid & 1;
  const int bm = blockIdx.x * 128;
  const int bn = blockIdx.y * 128;
  const int r0 = tid >> 2;
  const int c0 = (tid & 3) * 8;
  const int fr = lane & 15;
  const int fk = (lane >> 4) * 8;

  f32x4 acc[4][4] = {};

  const u16* ga = A + (size_t)(bm + r0) * K + c0;
  const u16* gb = Bw + (size_t)(bn + r0) * K + c0;

  for (int kt = 0; kt < K; kt += 32) {
    __syncthreads();
    __builtin_amdgcn_global_load_lds(
        (const __attribute__((address_space(1))) void*)(ga + kt),
        (__attribute__((address_space(3))) void*)(&As[r0 * 32 + c0]), 16, 0, 0);
    __builtin_amdgcn_global_load_lds(
        (const __attribute__((address_space(1))) void*)(ga + (size_t)64 * K + kt),
        (__attribute__((address_space(3))) void*)(&As[(r0 + 64) * 32 + c0]), 16, 0, 0);
    __builtin_amdgcn_global_load_lds(
        (const __attribute__((address_space(1))) void*)(gb + kt),
        (__attribute__((address_space(3))) void*)(&Bs[r0 * 32 + c0]), 16, 0, 0);
    __builtin_amdgcn_global_load_lds(
        (const __attribute__((address_space(1))) void*)(gb + (size_t)64 * K + kt),
        (__attribute__((address_space(3))) void*)(&Bs[(r0 + 64) * 32 + c0]), 16, 0, 0);
    __syncthreads();
    bf16x8 af[4], bfr[4];
#pragma unroll
    for (int m = 0; m < 4; ++m) af[m] = ld_bf8(&As[(wm * 64 + m * 16 + fr) * 32 + fk]);
#pragma unroll
    for (int n = 0; n < 4; ++n) bfr[n] = ld_bf8(&Bs[(wn * 64 + n * 16 + fr) * 32 + fk]);
#pragma unroll
    for (int m = 0; m < 4; ++m)
#pragma unroll
      for (int n = 0; n < 4; ++n)
        acc[m][n] = __builtin_amdgcn_mfma_f32_16x16x32_bf16(af[m], bfr[n], acc[m][n], 0, 0, 0);
  }

  const int cr = (lane >> 4) * 4;
  const int cc = lane & 15;
#pragma unroll
  for (int m = 0; m < 4; ++m) {
#pragma unroll
    for (int n = 0; n < 4; ++n) {
      const int colg = bn + wn * 64 + n * 16 + cc;
      const float bv = bias[colg];
      const int rbase = bm + wm * 64 + m * 16 + cr;
#pragma unroll
      for (int r = 0; r < 4; ++r)
        dst[(size_t)(rbase + r) * DM + colg] = acc[m][n][r] + bv;
    }
  }
}

// ---------------- fused flash attention (R12/R13 proven-best, frozen) ----------------
__global__ __launch_bounds__(256, 4) void k_attn(
    const u16* __restrict__ Qb, const u16* __restrict__ Kb, const u16* __restrict__ Vt,
    const float* __restrict__ bias, const u64* __restrict__ mpk,
    u16* __restrict__ ctx) {
  __shared__ u16 lds[2][2][4096];   // [buf][K, V][64*64]
  const int tid = threadIdx.x;
  const int lane = tid & 63;
  const int w = tid >> 6;
  const int b = blockIdx.z;
  const int h = blockIdx.y;
  const int q0 = blockIdx.x * 64 + w * 16;
  const int lq = lane & 15;
  const int lg = lane >> 4;

  const float* bp = bias + (size_t)h * S_LEN * S_LEN;
  const u16* Kp = Kb + (size_t)(b * NH + h) * S_LEN * DH;
  const u16* Vp = Vt + (size_t)(b * NH + h) * DH * S_LEN;

  bf16x8 qf[2];
  f32x4 cacc[4] = {};
  float m_run = -1e30f, l_run = 0.f;
  {
    const u16* Qp = Qb + (size_t)(b * NH + h) * S_LEN * DH;
    qf[0] = ld_bf8(&Qp[(size_t)(q0 + lq) * DH + lg * 8]);
    qf[1] = ld_bf8(&Qp[(size_t)(q0 + lq) * DH + 32 + lg * 8]);
  }

#define STAGE(ktv, cb) {                                                          \
    _Pragma("unroll") for (int i = 0; i < 2; ++i) {                               \
      const int el = (i * 256 + tid) * 8;                                         \
      const int rr = el >> 6;                                                     \
      const int ce = ((tid & 7) * 8) ^ ((rr & 7) << 3);                           \
      const u16* ksrc = Kp + (size_t)((ktv) + rr) * DH + ce;                      \
      const u16* vsrc = Vp + (size_t)rr * S_LEN + (ktv) + ce;                     \
      __builtin_amdgcn_global_load_lds(                                           \
          (const __attribute__((address_space(1))) void*)ksrc,                    \
          (__attribute__((address_space(3))) void*)&lds[cb][0][el], 16, 0, 0);    \
      __builtin_amdgcn_global_load_lds(                                           \
          (const __attribute__((address_space(1))) void*)vsrc,                    \
          (__attribute__((address_space(3))) void*)&lds[cb][1][el], 16, 0, 0);    \
    } }

#define SWZ(row, col) ((row) * 64 + (((((col) >> 3) ^ ((row) & 7)) << 3) | ((col) & 7)))

#define LOADB(ktv, tv) {                                                          \
    bv0 = *reinterpret_cast<const float4*>(                                       \
        &bp[(size_t)(q0 + lq) * S_LEN + (ktv) + 0 * 16 + lg * 4]);                \
    bv1 = *reinterpret_cast<const float4*>(                                       \
        &bp[(size_t)(q0 + lq) * S_LEN + (ktv) + 1 * 16 + lg * 4]);                \
    bv2 = *reinterpret_cast<const float4*>(                                       \
        &bp[(size_t)(q0 + lq) * S_LEN + (ktv) + 2 * 16 + lg * 4]);                \
    bv3 = *reinterpret_cast<const float4*>(                                       \
        &bp[(size_t)(q0 + lq) * S_LEN + (ktv) + 3 * 16 + lg * 4]);                \
    mw = mpk[((size_t)(b * S_LEN + q0 + lq)) * 32 + (tv)]; }

  float4 bv0, bv1, bv2, bv3;
  u64 mw;
  STAGE(0, 0);
  LOADB(0, 0);
  int c = 0;
  for (int t = 0; t < S_LEN / 64; ++t) {
    __syncthreads();                 // buf c staged; prev-iter LDS reads done
    if (t + 1 < S_LEN / 64) STAGE(t * 64 + 64, c ^ 1);

    // ---- S^T = K Q^T ----
    f32x4 sc[4];
    __builtin_amdgcn_s_setprio(1);
#pragma unroll
    for (int nb = 0; nb < 4; ++nb) {
      bf16x8 kf0 = ld_bf8(&lds[c][0][SWZ(nb * 16 + lq, lg * 8)]);
      bf16x8 kf1 = ld_bf8(&lds[c][0][SWZ(nb * 16 + lq, 32 + lg * 8)]);
      f32x4 z = {};
      z = __builtin_amdgcn_mfma_f32_16x16x32_bf16(kf0, qf[0], z, 0, 0, 0);
      sc[nb] = __builtin_amdgcn_mfma_f32_16x16x32_bf16(kf1, qf[1], z, 0, 0, 0);
    }
    __builtin_amdgcn_s_setprio(0);

    // ---- scale + bias + mask (k = nb*16 + lg*4 + r); consumes bv/mw ----
#pragma unroll
    for (int r = 0; r < 4; ++r) {
      const int sh = lg * 4 + r;
      sc[0][r] = ((mw >> (sh))      & 1) ? sc[0][r] * 0.125f + f4get(bv0, r) : -1e9f;
      sc[1][r] = ((mw >> (16 + sh)) & 1) ? sc[1][r] * 0.125f + f4get(bv1, r) : -1e9f;
      sc[2][r] = ((mw >> (32 + sh)) & 1) ? sc[2][r] * 0.125f + f4get(bv2, r) : -1e9f;
      sc[3][r] = ((mw >> (48 + sh)) & 1) ? sc[3][r] * 0.125f + f4get(bv3, r) : -1e9f;
    }
    // ---- issue next tile's bias/mask now (hides HBM latency to next use) ----
    if (t + 1 < S_LEN / 64) LOADB(t * 64 + 64, t + 1);

    // ---- max: in-lane tree + xor16 + xor32 ----
    float v0 = fmaxf(fmaxf(sc[0][0], sc[0][1]), fmaxf(sc[0][2], sc[0][3]));
    float v1 = fmaxf(fmaxf(sc[1][0], sc[1][1]), fmaxf(sc[1][2], sc[1][3]));
    float v2 = fmaxf(fmaxf(sc[2][0], sc[2][1]), fmaxf(sc[2][2], sc[2][3]));
    float v3 = fmaxf(fmaxf(sc[3][0], sc[3][1]), fmaxf(sc[3][2], sc[3][3]));
    float vm = fmaxf(fmaxf(v0, v1), fmaxf(v2, v3));
    vm = fmaxf(vm, __shfl_xor(vm, 16));
    vm = fmaxf(vm, __shfl_xor(vm, 32));
    if (!__all(vm <= m_run)) {
      const float mn = fmaxf(m_run, vm);
      const float corr = __expf(m_run - mn);
      m_run = mn;
      l_run *= corr;
      float cr_[4];
#pragma unroll
      for (int r = 0; r < 4; ++r) cr_[r] = __shfl(corr, lg * 4 + r);
#pragma unroll
      for (int nd = 0; nd < 4; ++nd)
#pragma unroll
        for (int r = 0; r < 4; ++r) cacc[nd][r] *= cr_[r];
    }
    // ---- exp + sum ----
    float s0 = 0.f;
#pragma unroll
    for (int nb = 0; nb < 4; ++nb)
#pragma unroll
      for (int r = 0; r < 4; ++r) {
        const float p = __expf(sc[nb][r] - m_run);
        sc[nb][r] = p;
        s0 += p;
      }
    s0 += __shfl_xor(s0, 16);
    s0 += __shfl_xor(s0, 32);
    l_run += s0;
    // ---- pack P in-lane (hardware cvt_pk via __bf16 casts) ----
    bf16x8 pa[2];
#pragma unroll
    for (int p = 0; p < 2; ++p) {
      union { __bf16 e[8]; bf16x8 v; } pu;
      pu.e[0] = (__bf16)sc[2 * p][0];     pu.e[1] = (__bf16)sc[2 * p][1];
      pu.e[2] = (__bf16)sc[2 * p][2];     pu.e[3] = (__bf16)sc[2 * p][3];
      pu.e[4] = (__bf16)sc[2 * p + 1][0]; pu.e[5] = (__bf16)sc[2 * p + 1][1];
      pu.e[6] = (__bf16)sc[2 * p + 1][2]; pu.e[7] = (__bf16)sc[2 * p + 1][3];
      pa[p] = pu.v;
    }
    // ---- ctx += P V ----
    __builtin_amdgcn_s_setprio(1);
#pragma unroll
    for (int nd = 0; nd < 4; ++nd) {
#pragma unroll
      for (int p = 0; p < 2; ++p) {
        union { unsigned u[4]; bf16x8 v; } vu;
        const unsigned* vp0 = reinterpret_cast<const unsigned*>(
            &lds[c][1][SWZ(nd * 16 + lq, (2 * p) * 16 + lg * 4)]);
        const unsigned* vp1 = reinterpret_cast<const unsigned*>(
            &lds[c][1][SWZ(nd * 16 + lq, (2 * p + 1) * 16 + lg * 4)]);
        vu.u[0] = vp0[0]; vu.u[1] = vp0[1];
        vu.u[2] = vp1[0]; vu.u[3] = vp1[1];
        cacc[nd] = __builtin_amdgcn_mfma_f32_16x16x32_bf16(pa[p], vu.v, cacc[nd], 0, 0, 0);
      }
    }
    __builtin_amdgcn_s_setprio(0);
    c ^= 1;
  }
#undef STAGE
#undef SWZ
#undef LOADB

  // ---- epilogue ----
#pragma unroll
  for (int r = 0; r < 4; ++r) {
    const float linv = 1.0f / __shfl(l_run, lg * 4 + r);
    const int tok = b * S_LEN + q0 + lg * 4 + r;
    u16* cp = ctx + (size_t)tok * DM + h * DH;
#pragma unroll
    for (int nd = 0; nd < 4; ++nd)
      cp[nd * 16 + lq] = f2bf(cacc[nd][r] * linv);
  }
}

extern "C" void kernel_launch(void* const* d_in, const int* in_sizes, int n_in,
                              void* d_out, int out_size, void* d_ws, size_t ws_size,
                              hipStream_t stream) {
  const float* q   = (const float*)d_in[0];
  const float* k   = (const float*)d_in[1];
  const float* v   = (const float*)d_in[2];
  const int*   msk = (const int*)d_in[3];
  const float* pb  = (const float*)d_in[4];
  const float* w_q = (const float*)d_in[5];
  const float* b_q = (const float*)d_in[6];
  const float* w_k = (const float*)d_in[7];
  const float* b_k = (const float*)d_in[8];
  const float* w_v = (const float*)d_in[9];
  const float* b_v = (const float*)d_in[10];
  const float* w_o = (const float*)d_in[11];
  const float* b_o = (const float*)d_in[12];
  float* out = (float*)d_out;

  char* ws = (char*)d_ws;
  u16* wq_bf = (u16*)(ws + ((size_t)0 << 20));
  u16* wk_bf = (u16*)(ws + ((size_t)2 << 20));
  u16* wv_bf = (u16*)(ws + ((size_t)4 << 20));
  u16* wo_bf = (u16*)(ws + ((size_t)6 << 20));
  u16* xq    = (u16*)(ws + ((size_t)8 << 20));   // reused as ctx after QKV gemm
  u16* xk    = (u16*)(ws + ((size_t)16 << 20));
  u16* xv    = (u16*)(ws + ((size_t)24 << 20));
  u16* Qb    = (u16*)(ws + ((size_t)32 << 20));
  u16* Kb    = (u16*)(ws + ((size_t)40 << 20));
  u16* Vtb   = (u16*)(ws + ((size_t)48 << 20));
  u64* mpk   = (u64*)(ws + ((size_t)56 << 20));  // 1 MB packed mask

  dim3 blk(256);
  const int n4w = DM * DM / 4;
  const int n4x = MTOK * DM / 4;

  k_convert_all<<<dim3(512, 7), blk, 0, stream>>>(
      w_q, w_k, w_v, w_o, q, k, v,
      wq_bf, wk_bf, wv_bf, wo_bf, xq, xk, xv, n4w, n4x);
  k_maskpack<<<dim3(2048), blk, 0, stream>>>(msk, mpk, 2 * S_LEN * S_LEN);

  k_gemm_qkv<<<dim3(32, 8, 3), blk, 0, stream>>>(
      xq, xk, xv, wq_bf, wk_bf, wv_bf, b_q, b_k, b_v, Qb, Kb, Vtb);

  k_attn<<<dim3(32, NH, 2), blk, 0, stream>>>(Qb, Kb, Vtb, pb, mpk, xq);
  k_gemm_out<<<dim3(32, 8), blk, 0, stream>>>(xq, wo_bf, b_o, out);
}

// Round 18
// 233.856 us; speedup vs baseline: 1.2980x; 1.0014x over previous
//
#include <hip/hip_runtime.h>
#include <hip/hip_bf16.h>

#define S_LEN 2048
#define DM 1024
#define NH 16
#define DH 64
#define MTOK 4096

typedef __attribute__((ext_vector_type(8))) __bf16 bf16x8;
typedef __attribute__((ext_vector_type(4))) float f32x4;
typedef unsigned short u16;
typedef unsigned long long u64;

__device__ __forceinline__ u16 f2bf(float f) {
  union { float f; unsigned u; } a; a.f = f;
  unsigned u = a.u;
  u += 0x7fffu + ((u >> 16) & 1u);   // RNE
  return (u16)(u >> 16);
}

__device__ __forceinline__ bf16x8 ld_bf8(const u16* p) {
  return *reinterpret_cast<const bf16x8*>(p);
}

// compile-time component access (no address-taking -> stays in registers, rule #20)
__device__ __forceinline__ float f4get(const float4& v, int r) {
  switch (r & 3) { case 0: return v.x; case 1: return v.y; case 2: return v.z; default: return v.w; }
}

// ---------------- fused fp32 -> bf16 convert: 7 arrays in one launch ----------------
__global__ void k_convert_all(
    const float* __restrict__ w_q, const float* __restrict__ w_k,
    const float* __restrict__ w_v, const float* __restrict__ w_o,
    const float* __restrict__ q, const float* __restrict__ k, const float* __restrict__ v,
    u16* __restrict__ dwq, u16* __restrict__ dwk, u16* __restrict__ dwv,
    u16* __restrict__ dwo, u16* __restrict__ dq, u16* __restrict__ dk, u16* __restrict__ dv,
    int n4w, int n4x) {
  const int z = blockIdx.y;
  const float* s; u16* d; int n4;
  switch (z) {
    case 0: s = w_q; d = dwq; n4 = n4w; break;
    case 1: s = w_k; d = dwk; n4 = n4w; break;
    case 2: s = w_v; d = dwv; n4 = n4w; break;
    case 3: s = w_o; d = dwo; n4 = n4w; break;
    case 4: s = q;   d = dq;  n4 = n4x; break;
    case 5: s = k;   d = dk;  n4 = n4x; break;
    default: s = v;  d = dv;  n4 = n4x; break;
  }
  int i = blockIdx.x * blockDim.x + threadIdx.x;
  const int stride = gridDim.x * blockDim.x;
  for (; i < n4; i += stride) {
    float4 vv = reinterpret_cast<const float4*>(s)[i];
    ushort4 o;
    o.x = f2bf(vv.x); o.y = f2bf(vv.y); o.z = f2bf(vv.z); o.w = f2bf(vv.w);
    reinterpret_cast<ushort4*>(d)[i] = o;
  }
}

// ---------------- mask bit-pack: [B][S][S] i32 -> [B][S][S/64] u64 ----------------
__global__ void k_maskpack(const int* __restrict__ m, u64* __restrict__ o, int n) {
  int i = blockIdx.x * blockDim.x + threadIdx.x;
  int stride = gridDim.x * blockDim.x;
  for (; i < n; i += stride) {
    u64 bal = __ballot(m[i] != 0);
    if ((i & 63) == 0) o[i >> 6] = bal;
  }
}

// ---------------- fused QKV GEMM: z = 0 (Q), 1 (K), 2 (V, transposed out) ----------
__global__ __launch_bounds__(256) void k_gemm_qkv(
    const u16* __restrict__ xq, const u16* __restrict__ xk, const u16* __restrict__ xv,
    const u16* __restrict__ wq, const u16* __restrict__ wk, const u16* __restrict__ wv,
    const float* __restrict__ bq, const float* __restrict__ bk, const float* __restrict__ bvb,
    u16* __restrict__ Qd, u16* __restrict__ Kd, u16* __restrict__ Vd) {
  constexpr int K = DM;
  __shared__ u16 As[128 * 32];
  __shared__ u16 Bs[128 * 32];
  const int z = blockIdx.z;
  const u16* A  = z == 0 ? xq : z == 1 ? xk : xv;
  const u16* Bw = z == 0 ? wq : z == 1 ? wk : wv;
  const float* bias = z == 0 ? bq : z == 1 ? bk : bvb;
  const int tid = threadIdx.x;
  const int lane = tid & 63;
  const int wid = tid >> 6;
  const int wm = wid >> 1, wn = wid & 1;
  const int bm = blockIdx.x * 128;
  const int bn = blockIdx.y * 128;
  const int r0 = tid >> 2;
  const int c0 = (tid & 3) * 8;
  const int fr = lane & 15;
  const int fk = (lane >> 4) * 8;

  f32x4 acc[4][4] = {};

  const u16* ga = A + (size_t)(bm + r0) * K + c0;
  const u16* gb = Bw + (size_t)(bn + r0) * K + c0;

  for (int kt = 0; kt < K; kt += 32) {
    __syncthreads();
    __builtin_amdgcn_global_load_lds(
        (const __attribute__((address_space(1))) void*)(ga + kt),
        (__attribute__((address_space(3))) void*)(&As[r0 * 32 + c0]), 16, 0, 0);
    __builtin_amdgcn_global_load_lds(
        (const __attribute__((address_space(1))) void*)(ga + (size_t)64 * K + kt),
        (__attribute__((address_space(3))) void*)(&As[(r0 + 64) * 32 + c0]), 16, 0, 0);
    __builtin_amdgcn_global_load_lds(
        (const __attribute__((address_space(1))) void*)(gb + kt),
        (__attribute__((address_space(3))) void*)(&Bs[r0 * 32 + c0]), 16, 0, 0);
    __builtin_amdgcn_global_load_lds(
        (const __attribute__((address_space(1))) void*)(gb + (size_t)64 * K + kt),
        (__attribute__((address_space(3))) void*)(&Bs[(r0 + 64) * 32 + c0]), 16, 0, 0);
    __syncthreads();
    bf16x8 af[4], bfr[4];
#pragma unroll
    for (int m = 0; m < 4; ++m) af[m] = ld_bf8(&As[(wm * 64 + m * 16 + fr) * 32 + fk]);
#pragma unroll
    for (int n = 0; n < 4; ++n) bfr[n] = ld_bf8(&Bs[(wn * 64 + n * 16 + fr) * 32 + fk]);
#pragma unroll
    for (int m = 0; m < 4; ++m)
#pragma unroll
      for (int n = 0; n < 4; ++n)
        acc[m][n] = __builtin_amdgcn_mfma_f32_16x16x32_bf16(af[m], bfr[n], acc[m][n], 0, 0, 0);
  }

  const int cr = (lane >> 4) * 4;
  const int cc = lane & 15;
#pragma unroll
  for (int m = 0; m < 4; ++m) {
#pragma unroll
    for (int n = 0; n < 4; ++n) {
      const int colg = bn + wn * 64 + n * 16 + cc;
      const float bv = bias[colg];
      const int rbase = bm + wm * 64 + m * 16 + cr;
      const int hh = colg >> 6, d = colg & 63;
      if (z < 2) {
        u16* o = z == 0 ? Qd : Kd;
#pragma unroll
        for (int r = 0; r < 4; ++r) {
          const int tok = rbase + r;
          const int b = tok >> 11, s = tok & 2047;
          o[(((size_t)(b * NH + hh) * S_LEN) + s) * DH + d] = f2bf(acc[m][n][r] + bv);
        }
      } else {
        const int tok = rbase;
        const int b = tok >> 11, s = tok & 2047;
        ushort4 pk;
        pk.x = f2bf(acc[m][n][0] + bv);
        pk.y = f2bf(acc[m][n][1] + bv);
        pk.z = f2bf(acc[m][n][2] + bv);
        pk.w = f2bf(acc[m][n][3] + bv);
        *reinterpret_cast<ushort4*>(&Vd[(((size_t)(b * NH + hh) * DH) + d) * S_LEN + s]) = pk;
      }
    }
  }
}

// ------- output GEMM: C = ctx @ Wo^T + bias (fp32 out), 64x128 tile ---------
// BM=64 halves the tile -> grid (64,8) = 512 blocks = 2 blocks/CU (was 1):
// co-resident block fills the barrier/vmcnt drains. Waves 2x2 over 32x64.
__global__ __launch_bounds__(256) void k_gemm_out(
    const u16* __restrict__ A, const u16* __restrict__ Bw,
    const float* __restrict__ bias, float* __restrict__ dst) {
  constexpr int K = DM;
  __shared__ u16 As[64 * 32];
  __shared__ u16 Bs[128 * 32];
  const int tid = threadIdx.x;
  const int lane = tid & 63;
  const int wid = tid >> 6;
  const int wm = wid >> 1, wn = wid & 1;   // 2x2 waves: 32-row x 64-col each
  const int bm = blockIdx.x * 64;
  const int bn = blockIdx.y * 128;
  const int r0 = tid >> 2;
  const int c0 = (tid & 3) * 8;
  const int fr = lane & 15;
  const int fk = (lane >> 4) * 8;

  f32x4 acc[2][4] = {};

  const u16* ga = A + (size_t)(bm + r0) * K + c0;   // r0 0..63 covers 64 rows
  const u16* gb = Bw + (size_t)(bn + r0) * K + c0;

  for (int kt = 0; kt < K; kt += 32) {
    __syncthreads();
    __builtin_amdgcn_global_load_lds(
        (const __attribute__((address_space(1))) void*)(ga + kt),
        (__attribute__((address_space(3))) void*)(&As[r0 * 32 + c0]), 16, 0, 0);
    __builtin_amdgcn_global_load_lds(
        (const __attribute__((address_space(1))) void*)(gb + kt),
        (__attribute__((address_space(3))) void*)(&Bs[r0 * 32 + c0]), 16, 0, 0);
    __builtin_amdgcn_global_load_lds(
        (const __attribute__((address_space(1))) void*)(gb + (size_t)64 * K + kt),
        (__attribute__((address_space(3))) void*)(&Bs[(r0 + 64) * 32 + c0]), 16, 0, 0);
    __syncthreads();
    bf16x8 af[2], bfr[4];
#pragma unroll
    for (int m = 0; m < 2; ++m) af[m] = ld_bf8(&As[(wm * 32 + m * 16 + fr) * 32 + fk]);
#pragma unroll
    for (int n = 0; n < 4; ++n) bfr[n] = ld_bf8(&Bs[(wn * 64 + n * 16 + fr) * 32 + fk]);
#pragma unroll
    for (int m = 0; m < 2; ++m)
#pragma unroll
      for (int n = 0; n < 4; ++n)
        acc[m][n] = __builtin_amdgcn_mfma_f32_16x16x32_bf16(af[m], bfr[n], acc[m][n], 0, 0, 0);
  }

  const int cr = (lane >> 4) * 4;
  const int cc = lane & 15;
#pragma unroll
  for (int m = 0; m < 2; ++m) {
#pragma unroll
    for (int n = 0; n < 4; ++n) {
      const int colg = bn + wn * 64 + n * 16 + cc;
      const float bv = bias[colg];
      const int rbase = bm + wm * 32 + m * 16 + cr;
#pragma unroll
      for (int r = 0; r < 4; ++r)
        dst[(size_t)(rbase + r) * DM + colg] = acc[m][n][r] + bv;
    }
  }
}

// ---------------- fused flash attention (R12/R13 proven-best, frozen) ----------------
__global__ __launch_bounds__(256, 4) void k_attn(
    const u16* __restrict__ Qb, const u16* __restrict__ Kb, const u16* __restrict__ Vt,
    const float* __restrict__ bias, const u64* __restrict__ mpk,
    u16* __restrict__ ctx) {
  __shared__ u16 lds[2][2][4096];   // [buf][K, V][64*64]
  const int tid = threadIdx.x;
  const int lane = tid & 63;
  const int w = tid >> 6;
  const int b = blockIdx.z;
  const int h = blockIdx.y;
  const int q0 = blockIdx.x * 64 + w * 16;
  const int lq = lane & 15;
  const int lg = lane >> 4;

  const float* bp = bias + (size_t)h * S_LEN * S_LEN;
  const u16* Kp = Kb + (size_t)(b * NH + h) * S_LEN * DH;
  const u16* Vp = Vt + (size_t)(b * NH + h) * DH * S_LEN;

  bf16x8 qf[2];
  f32x4 cacc[4] = {};
  float m_run = -1e30f, l_run = 0.f;
  {
    const u16* Qp = Qb + (size_t)(b * NH + h) * S_LEN * DH;
    qf[0] = ld_bf8(&Qp[(size_t)(q0 + lq) * DH + lg * 8]);
    qf[1] = ld_bf8(&Qp[(size_t)(q0 + lq) * DH + 32 + lg * 8]);
  }

#define STAGE(ktv, cb) {                                                          \
    _Pragma("unroll") for (int i = 0; i < 2; ++i) {                               \
      const int el = (i * 256 + tid) * 8;                                         \
      const int rr = el >> 6;                                                     \
      const int ce = ((tid & 7) * 8) ^ ((rr & 7) << 3);                           \
      const u16* ksrc = Kp + (size_t)((ktv) + rr) * DH + ce;                      \
      const u16* vsrc = Vp + (size_t)rr * S_LEN + (ktv) + ce;                     \
      __builtin_amdgcn_global_load_lds(                                           \
          (const __attribute__((address_space(1))) void*)ksrc,                    \
          (__attribute__((address_space(3))) void*)&lds[cb][0][el], 16, 0, 0);    \
      __builtin_amdgcn_global_load_lds(                                           \
          (const __attribute__((address_space(1))) void*)vsrc,                    \
          (__attribute__((address_space(3))) void*)&lds[cb][1][el], 16, 0, 0);    \
    } }

#define SWZ(row, col) ((row) * 64 + (((((col) >> 3) ^ ((row) & 7)) << 3) | ((col) & 7)))

#define LOADB(ktv, tv) {                                                          \
    bv0 = *reinterpret_cast<const float4*>(                                       \
        &bp[(size_t)(q0 + lq) * S_LEN + (ktv) + 0 * 16 + lg * 4]);                \
    bv1 = *reinterpret_cast<const float4*>(                                       \
        &bp[(size_t)(q0 + lq) * S_LEN + (ktv) + 1 * 16 + lg * 4]);                \
    bv2 = *reinterpret_cast<const float4*>(                                       \
        &bp[(size_t)(q0 + lq) * S_LEN + (ktv) + 2 * 16 + lg * 4]);                \
    bv3 = *reinterpret_cast<const float4*>(                                       \
        &bp[(size_t)(q0 + lq) * S_LEN + (ktv) + 3 * 16 + lg * 4]);                \
    mw = mpk[((size_t)(b * S_LEN + q0 + lq)) * 32 + (tv)]; }

  float4 bv0, bv1, bv2, bv3;
  u64 mw;
  STAGE(0, 0);
  LOADB(0, 0);
  int c = 0;
  for (int t = 0; t < S_LEN / 64; ++t) {
    __syncthreads();                 // buf c staged; prev-iter LDS reads done
    if (t + 1 < S_LEN / 64) STAGE(t * 64 + 64, c ^ 1);

    // ---- S^T = K Q^T ----
    f32x4 sc[4];
    __builtin_amdgcn_s_setprio(1);
#pragma unroll
    for (int nb = 0; nb < 4; ++nb) {
      bf16x8 kf0 = ld_bf8(&lds[c][0][SWZ(nb * 16 + lq, lg * 8)]);
      bf16x8 kf1 = ld_bf8(&lds[c][0][SWZ(nb * 16 + lq, 32 + lg * 8)]);
      f32x4 z = {};
      z = __builtin_amdgcn_mfma_f32_16x16x32_bf16(kf0, qf[0], z, 0, 0, 0);
      sc[nb] = __builtin_amdgcn_mfma_f32_16x16x32_bf16(kf1, qf[1], z, 0, 0, 0);
    }
    __builtin_amdgcn_s_setprio(0);

    // ---- scale + bias + mask (k = nb*16 + lg*4 + r); consumes bv/mw ----
#pragma unroll
    for (int r = 0; r < 4; ++r) {
      const int sh = lg * 4 + r;
      sc[0][r] = ((mw >> (sh))      & 1) ? sc[0][r] * 0.125f + f4get(bv0, r) : -1e9f;
      sc[1][r] = ((mw >> (16 + sh)) & 1) ? sc[1][r] * 0.125f + f4get(bv1, r) : -1e9f;
      sc[2][r] = ((mw >> (32 + sh)) & 1) ? sc[2][r] * 0.125f + f4get(bv2, r) : -1e9f;
      sc[3][r] = ((mw >> (48 + sh)) & 1) ? sc[3][r] * 0.125f + f4get(bv3, r) : -1e9f;
    }
    // ---- issue next tile's bias/mask now (hides HBM latency to next use) ----
    if (t + 1 < S_LEN / 64) LOADB(t * 64 + 64, t + 1);

    // ---- max: in-lane tree + xor16 + xor32 ----
    float v0 = fmaxf(fmaxf(sc[0][0], sc[0][1]), fmaxf(sc[0][2], sc[0][3]));
    float v1 = fmaxf(fmaxf(sc[1][0], sc[1][1]), fmaxf(sc[1][2], sc[1][3]));
    float v2 = fmaxf(fmaxf(sc[2][0], sc[2][1]), fmaxf(sc[2][2], sc[2][3]));
    float v3 = fmaxf(fmaxf(sc[3][0], sc[3][1]), fmaxf(sc[3][2], sc[3][3]));
    float vm = fmaxf(fmaxf(v0, v1), fmaxf(v2, v3));
    vm = fmaxf(vm, __shfl_xor(vm, 16));
    vm = fmaxf(vm, __shfl_xor(vm, 32));
    if (!__all(vm <= m_run)) {
      const float mn = fmaxf(m_run, vm);
      const float corr = __expf(m_run - mn);
      m_run = mn;
      l_run *= corr;
      float cr_[4];
#pragma unroll
      for (int r = 0; r < 4; ++r) cr_[r] = __shfl(corr, lg * 4 + r);
#pragma unroll
      for (int nd = 0; nd < 4; ++nd)
#pragma unroll
        for (int r = 0; r < 4; ++r) cacc[nd][r] *= cr_[r];
    }
    // ---- exp + sum ----
    float s0 = 0.f;
#pragma unroll
    for (int nb = 0; nb < 4; ++nb)
#pragma unroll
      for (int r = 0; r < 4; ++r) {
        const float p = __expf(sc[nb][r] - m_run);
        sc[nb][r] = p;
        s0 += p;
      }
    s0 += __shfl_xor(s0, 16);
    s0 += __shfl_xor(s0, 32);
    l_run += s0;
    // ---- pack P in-lane (hardware cvt_pk via __bf16 casts) ----
    bf16x8 pa[2];
#pragma unroll
    for (int p = 0; p < 2; ++p) {
      union { __bf16 e[8]; bf16x8 v; } pu;
      pu.e[0] = (__bf16)sc[2 * p][0];     pu.e[1] = (__bf16)sc[2 * p][1];
      pu.e[2] = (__bf16)sc[2 * p][2];     pu.e[3] = (__bf16)sc[2 * p][3];
      pu.e[4] = (__bf16)sc[2 * p + 1][0]; pu.e[5] = (__bf16)sc[2 * p + 1][1];
      pu.e[6] = (__bf16)sc[2 * p + 1][2]; pu.e[7] = (__bf16)sc[2 * p + 1][3];
      pa[p] = pu.v;
    }
    // ---- ctx += P V ----
    __builtin_amdgcn_s_setprio(1);
#pragma unroll
    for (int nd = 0; nd < 4; ++nd) {
#pragma unroll
      for (int p = 0; p < 2; ++p) {
        union { unsigned u[4]; bf16x8 v; } vu;
        const unsigned* vp0 = reinterpret_cast<const unsigned*>(
            &lds[c][1][SWZ(nd * 16 + lq, (2 * p) * 16 + lg * 4)]);
        const unsigned* vp1 = reinterpret_cast<const unsigned*>(
            &lds[c][1][SWZ(nd * 16 + lq, (2 * p + 1) * 16 + lg * 4)]);
        vu.u[0] = vp0[0]; vu.u[1] = vp0[1];
        vu.u[2] = vp1[0]; vu.u[3] = vp1[1];
        cacc[nd] = __builtin_amdgcn_mfma_f32_16x16x32_bf16(pa[p], vu.v, cacc[nd], 0, 0, 0);
      }
    }
    __builtin_amdgcn_s_setprio(0);
    c ^= 1;
  }
#undef STAGE
#undef SWZ
#undef LOADB

  // ---- epilogue ----
#pragma unroll
  for (int r = 0; r < 4; ++r) {
    const float linv = 1.0f / __shfl(l_run, lg * 4 + r);
    const int tok = b * S_LEN + q0 + lg * 4 + r;
    u16* cp = ctx + (size_t)tok * DM + h * DH;
#pragma unroll
    for (int nd = 0; nd < 4; ++nd)
      cp[nd * 16 + lq] = f2bf(cacc[nd][r] * linv);
  }
}

extern "C" void kernel_launch(void* const* d_in, const int* in_sizes, int n_in,
                              void* d_out, int out_size, void* d_ws, size_t ws_size,
                              hipStream_t stream) {
  const float* q   = (const float*)d_in[0];
  const float* k   = (const float*)d_in[1];
  const float* v   = (const float*)d_in[2];
  const int*   msk = (const int*)d_in[3];
  const float* pb  = (const float*)d_in[4];
  const float* w_q = (const float*)d_in[5];
  const float* b_q = (const float*)d_in[6];
  const float* w_k = (const float*)d_in[7];
  const float* b_k = (const float*)d_in[8];
  const float* w_v = (const float*)d_in[9];
  const float* b_v = (const float*)d_in[10];
  const float* w_o = (const float*)d_in[11];
  const float* b_o = (const float*)d_in[12];
  float* out = (float*)d_out;

  char* ws = (char*)d_ws;
  u16* wq_bf = (u16*)(ws + ((size_t)0 << 20));
  u16* wk_bf = (u16*)(ws + ((size_t)2 << 20));
  u16* wv_bf = (u16*)(ws + ((size_t)4 << 20));
  u16* wo_bf = (u16*)(ws + ((size_t)6 << 20));
  u16* xq    = (u16*)(ws + ((size_t)8 << 20));   // reused as ctx after QKV gemm
  u16* xk    = (u16*)(ws + ((size_t)16 << 20));
  u16* xv    = (u16*)(ws + ((size_t)24 << 20));
  u16* Qb    = (u16*)(ws + ((size_t)32 << 20));
  u16* Kb    = (u16*)(ws + ((size_t)40 << 20));
  u16* Vtb   = (u16*)(ws + ((size_t)48 << 20));
  u64* mpk   = (u64*)(ws + ((size_t)56 << 20));  // 1 MB packed mask

  dim3 blk(256);
  const int n4w = DM * DM / 4;
  const int n4x = MTOK * DM / 4;

  k_convert_all<<<dim3(512, 7), blk, 0, stream>>>(
      w_q, w_k, w_v, w_o, q, k, v,
      wq_bf, wk_bf, wv_bf, wo_bf, xq, xk, xv, n4w, n4x);
  k_maskpack<<<dim3(2048), blk, 0, stream>>>(msk, mpk, 2 * S_LEN * S_LEN);

  k_gemm_qkv<<<dim3(32, 8, 3), blk, 0, stream>>>(
      xq, xk, xv, wq_bf, wk_bf, wv_bf, b_q, b_k, b_v, Qb, Kb, Vtb);

  k_attn<<<dim3(32, NH, 2), blk, 0, stream>>>(Qb, Kb, Vtb, pb, mpk, xq);
  k_gemm_out<<<dim3(64, 8), blk, 0, stream>>>(xq, wo_bf, b_o, out);
}